// Round 1
// baseline (423.337 us; speedup 1.0000x reference)
//
#include <hip/hip_runtime.h>

// channel_attention: einsum('bocs,bocm->bocs', x, softmax(score)) contracts m which
// only appears in score => multiplies x by softmax row-sum == 1 (within fp32 eps).
// So q/k/atten are dead code and the problem is exactly:
//   out[g,c,s] = LN_c( sum_m Wp[c][m] * x[g][m][s] + bp[c] ) * gp[c] + betap[c]
// g = b*o in [0,128). Per group: GEMM M=C=128, N=3000, K=128, + per-column LN.
//
// V2 changes vs 149us/dispatch baseline (latency-bound: occ 21%, HBM 26%, all pipes idle):
//  - W no longer staged in LDS: it is 32KB, shared by all 3072 blocks, L1/L2-resident.
//    B-fragments read directly from global (16 x 64B lines per load instr). LDS 64->32KB
//    => 4 blocks/CU (launch_bounds(256,4)), 2x the waves to hide HBM latency.
//  - MFMA operands swapped: D = X^T * W^T = out^T tile, so each lane's f4 acc holds
//    4 CONSECUTIVE s at one channel c -> epilogue is 16 f4 stores (was 64 scalar).
//    LDS/global fragment reads are identical in layout; LN reduce moves to the
//    col axis (shfl_xor 1/2/4/8 within 16-lane groups).
//  - f32->bf16 staging conversion via v_cvt_pk_bf16_f32 (1 op / 2 elems, RNE),
//    replacing ~600 manual VALU ops/thread with 64.

#define C    128
#define SEQ  3000
#define NG   128
#define NT   128                       // columns per block
#define NBLK ((SEQ + NT - 1) / NT)     // 24

typedef float f4 __attribute__((ext_vector_type(4)));
typedef short short8 __attribute__((ext_vector_type(8)));

__device__ __forceinline__ unsigned short f2bf(float f) {
    union { float f; unsigned u; } v; v.f = f;
    unsigned r = v.u + 0x7fffu + ((v.u >> 16) & 1u);   // RNE
    return (unsigned short)(r >> 16);
}

// packed f32x2 -> bf16x2, RNE; dst.lo = bf16(lo), dst.hi = bf16(hi)
__device__ __forceinline__ unsigned cvt2(float lo, float hi) {
    unsigned r;
    asm("v_cvt_pk_bf16_f32 %0, %1, %2" : "=v"(r) : "v"(lo), "v"(hi));
    return r;
}

// 16B-chunk XOR swizzle: injective over 16 consecutive rows (frag reads) and over
// the transpose-write lane pattern, both verified <=2-way.
__device__ __forceinline__ int swz(int row, int chunk) {
    return chunk ^ ((row ^ (row >> 2)) & 15);
}

__global__ void cvt_wp(const float* __restrict__ Wp, unsigned short* __restrict__ out) {
    int i = blockIdx.x * 256 + threadIdx.x;
    if (i < C * C) out[i] = f2bf(Wp[i]);
}

__global__ __launch_bounds__(256, 4) void gemm_ln_mfma(
    const float* __restrict__ x,             // [NG][C][SEQ] fp32
    const unsigned short* __restrict__ wbf,  // [C][C] bf16 (c-major, m contiguous)
    const float* __restrict__ bp,
    const float* __restrict__ gp,
    const float* __restrict__ bep,
    float* __restrict__ out)                 // [NG][C][SEQ] fp32
{
    __shared__ __align__(16) unsigned short Xl[NT * C];  // 32 KB, [s][m] swizzled

    const int g  = blockIdx.y;
    const int s0 = blockIdx.x * NT;
    const float* xg = x + (size_t)g * (C * SEQ);
    float* og = out + (size_t)g * (C * SEQ);
    const int t = threadIdx.x;

    // ---- stage X transposed: thread owns (m-chunk, s-quad); 8x4 in-register
    // transpose; writes 4 x 16B rows of 8 bf16 (m contiguous).
    {
        const int sq  = t & 31;              // s-quad 0..31 (consecutive lanes -> coalesced)
        const int mcb = t >> 5;              // 0..7
        const int s_loc  = 4 * sq;
        const int s_glob = s0 + s_loc;
        const bool valid = (s_glob + 3) < SEQ;
        #pragma unroll
        for (int half = 0; half < 2; ++half) {
            const int mc = mcb + 8 * half;   // m-chunk 0..15
            f4 r[8];
            const float* xp = xg + (size_t)(mc * 8) * SEQ + s_glob;
            #pragma unroll
            for (int rr = 0; rr < 8; ++rr) {
                if (valid) r[rr] = *(const f4*)(xp + (size_t)rr * SEQ);
                else       r[rr] = (f4){0.f, 0.f, 0.f, 0.f};
            }
            #pragma unroll
            for (int j = 0; j < 4; ++j) {
                const int sl = s_loc + j;
                uint4 pk;
                pk.x = cvt2(r[0][j], r[1][j]);
                pk.y = cvt2(r[2][j], r[3][j]);
                pk.z = cvt2(r[4][j], r[5][j]);
                pk.w = cvt2(r[6][j], r[7][j]);
                *(uint4*)&Xl[sl * C + swz(sl, mc) * 8] = pk;
            }
        }
    }
    __syncthreads();

    // ---- MFMA: wave owns 32-row s-strip x all 128 channels.
    // A = X^T (M=s), B = W^T (N=c, read straight from global; L1/L2-resident,
    // each load instr = 16 channels x one 64B line). D[s][c]: col=c, row=s,
    // so acc f4 = 4 consecutive s at one c.
    const int w    = t >> 6;
    const int lane = t & 63;
    const int col  = lane & 15;
    const int quad = lane >> 4;

    f4 acc[2][8];   // [nt = s-tile][mt = c-tile]
    #pragma unroll
    for (int nt = 0; nt < 2; ++nt)
        #pragma unroll
        for (int mt = 0; mt < 8; ++mt) acc[nt][mt] = (f4){0.f, 0.f, 0.f, 0.f};

    const unsigned short* wl = wbf + col * C + quad * 8;

    #pragma unroll 1
    for (int kc = 0; kc < 4; ++kc) {
        short8 a[2], b[8];
        #pragma unroll
        for (int nt = 0; nt < 2; ++nt) {
            const int srow = 32 * w + 16 * nt + col;
            a[nt] = *(const short8*)&Xl[srow * C + swz(srow, 4 * kc + quad) * 8];
        }
        #pragma unroll
        for (int mt = 0; mt < 8; ++mt)
            b[mt] = *(const short8*)(wl + mt * 16 * C + kc * 32);
        #pragma unroll
        for (int nt = 0; nt < 2; ++nt)
            #pragma unroll
            for (int mt = 0; mt < 8; ++mt)
                acc[nt][mt] = __builtin_amdgcn_mfma_f32_16x16x32_bf16(
                    a[nt], b[mt], acc[nt][mt], 0, 0, 0);
    }

    // ---- per-lane channel params (c = 16*mt + col)
    float bl[8], gl[8], el[8];
    #pragma unroll
    for (int mt = 0; mt < 8; ++mt) {
        const int c = 16 * mt + col;
        bl[mt] = bp[c]; gl[mt] = gp[c]; el[mt] = bep[c];
    }

    // ---- bias + per-s LayerNorm over c (in-reg over mt, cross-lane over col)
    #pragma unroll
    for (int nt = 0; nt < 2; ++nt)
        #pragma unroll
        for (int mt = 0; mt < 8; ++mt)
            #pragma unroll
            for (int r = 0; r < 4; ++r) acc[nt][mt][r] += bl[mt];

    float mean[2][4], rstd[2][4];
    #pragma unroll
    for (int nt = 0; nt < 2; ++nt)
        #pragma unroll
        for (int r = 0; r < 4; ++r) {
            float s = 0.f, q = 0.f;
            #pragma unroll
            for (int mt = 0; mt < 8; ++mt) {
                float y = acc[nt][mt][r];
                s += y; q += y * y;
            }
            s += __shfl_xor(s, 1); q += __shfl_xor(q, 1);
            s += __shfl_xor(s, 2); q += __shfl_xor(q, 2);
            s += __shfl_xor(s, 4); q += __shfl_xor(q, 4);
            s += __shfl_xor(s, 8); q += __shfl_xor(q, 8);
            float m = s * (1.0f / C);
            float v = q * (1.0f / C) - m * m;
            mean[nt][r] = m;
            rstd[nt][r] = rsqrtf(v + 1e-5f);
        }

    // ---- scale/shift + vectorized store: one f4 = 4 consecutive s at fixed c
    #pragma unroll
    for (int nt = 0; nt < 2; ++nt) {
        const int sg = s0 + 32 * w + 16 * nt + 4 * quad;   // mult of 4; SEQ mult of 4
        if (sg < SEQ) {
            #pragma unroll
            for (int mt = 0; mt < 8; ++mt) {
                const int c = 16 * mt + col;
                f4 v;
                #pragma unroll
                for (int r = 0; r < 4; ++r)
                    v[r] = (acc[nt][mt][r] - mean[nt][r]) * rstd[nt][r] * gl[mt] + el[mt];
                *(f4*)&og[(size_t)c * SEQ + sg] = v;
            }
        }
    }
}

extern "C" void kernel_launch(void* const* d_in, const int* in_sizes, int n_in,
                              void* d_out, int out_size, void* d_ws, size_t ws_size,
                              hipStream_t stream) {
    // inputs: x, Wq, bq, gq, betaq, Wk, bk, gk, betak, Wp, bp, gp, betap
    const float* x   = (const float*)d_in[0];
    const float* Wp  = (const float*)d_in[9];
    const float* bp  = (const float*)d_in[10];
    const float* gp  = (const float*)d_in[11];
    const float* bep = (const float*)d_in[12];
    float* out = (float*)d_out;
    unsigned short* wbf = (unsigned short*)d_ws;   // 32 KB bf16 weights

    hipLaunchKernelGGL(cvt_wp, dim3(64), dim3(256), 0, stream, Wp, wbf);

    dim3 grid(NBLK, NG);
    hipLaunchKernelGGL(gemm_ln_mfma, grid, dim3(256), 0, stream,
                       x, wbf, bp, gp, bep, out);
}